// Round 1
// baseline (599.119 us; speedup 1.0000x reference)
//
#include <hip/hip_runtime.h>

#define NI 50000
#define NL 400000
#define EPO 400000
#define EADJ 200000

typedef unsigned int u32;
typedef unsigned short u16;
typedef short bf16x8 __attribute__((ext_vector_type(8)));
typedef float f32x4 __attribute__((ext_vector_type(4)));

__device__ __forceinline__ float bf2f(u16 h){ return __uint_as_float(((u32)h)<<16); }
__device__ __forceinline__ u16 f2bf(float f){
  u32 u = __float_as_uint(f);
  u += 0x7FFFu + ((u>>16)&1u);
  return (u16)(u>>16);
}
__device__ __forceinline__ float wsum(float v){
#pragma unroll
  for(int o=32;o>0;o>>=1) v += __shfl_xor(v,o,64);
  return v;
}

// ---------------- K_zero: zero the count arrays ----------------
__global__ __launch_bounds__(256) void kz(int* __restrict__ p, int n){
  int i = blockIdx.x*256 + threadIdx.x;
  if(i<n) p[i]=0;
}

// ---------------- K0: weight prep ----------------
// v4[which][h*64+c] = sum_j W[c,h*64+j]*att[h,j]   which: 0=src_po 1=dst_po 2=src_adj 3=dst_adj
// WbigT[m][k] (256x512 bf16): block-diag of Wsrc_po (k<256) / Wsrc_adj (k>=256)
// B2T[m][k]  (256x320 bf16): [inter|h0] -> [r_sum z_sum i_n h_n]
__global__ __launch_bounds__(256) void k0_prep(
    const float* __restrict__ Wsrc_po, const float* __restrict__ att_src_po,
    const float* __restrict__ Wdst_po, const float* __restrict__ att_dst_po,
    const float* __restrict__ Wsrc_adj, const float* __restrict__ att_src_adj,
    const float* __restrict__ Wdst_adj, const float* __restrict__ att_dst_adj,
    const float* __restrict__ W_ih, const float* __restrict__ W_hh,
    const float* __restrict__ bias_po, const float* __restrict__ bias_adj,
    const float* __restrict__ b_ih, const float* __restrict__ b_hh,
    float* __restrict__ v4, u16* __restrict__ WbigT, u16* __restrict__ B2T,
    float* __restrict__ bias_comb, float* __restrict__ bias2)
{
  const int T0 = 1024, T1 = 256*512, T2 = 256*320;
  int total = T0 + T1 + T2 + 256 + 256;
  for(int t = blockIdx.x*256 + threadIdx.x; t < total; t += gridDim.x*256){
    if(t < T0){
      int which = t>>8, hc = t&255, h = hc>>6, c = hc&63;
      const float *W, *att;
      if(which==0){ W=Wsrc_po;  att=att_src_po; }
      else if(which==1){ W=Wdst_po;  att=att_dst_po; }
      else if(which==2){ W=Wsrc_adj; att=att_src_adj; }
      else { W=Wdst_adj; att=att_dst_adj; }
      float s=0.f;
      for(int j=0;j<64;j++) s += W[c*256 + h*64 + j]*att[h*64+j];
      v4[which*256 + hc] = s;
    } else if(t < T0 + T1){
      int i = t - T0; int m = i>>9, k = i&511;
      float val = 0.f;
      if(k < 256){ if((k>>6)==(m>>6)) val = Wsrc_po[(k&63)*256 + m]; }
      else { int k2=k-256; if((k2>>6)==(m>>6)) val = Wsrc_adj[(k2&63)*256 + m]; }
      WbigT[m*512+k] = f2bf(val);
    } else if(t < T0 + T1 + T2){
      int i = t - (T0+T1); int m = i/320, k = i - m*320;
      float val = 0.f;
      if(k < 256){ if(m<192) val = W_ih[m*256+k]; }
      else { int kk=k-256;
        if(m<128) val = W_hh[m*64+kk];
        else if(m>=192) val = W_hh[(m-64)*64+kk];
      }
      B2T[m*320+k] = f2bf(val);
    } else if(t < T0 + T1 + T2 + 256){
      int m = t - (T0+T1+T2);
      bias_comb[m] = bias_po[m] + bias_adj[m];
    } else {
      int m = t - (T0+T1+T2+256);
      float v;
      if(m<128) v = b_ih[m] + b_hh[m];
      else if(m<192) v = b_ih[m];
      else v = b_hh[m-64];
      bias2[m] = v;
    }
  }
}

// ---------------- K1: lane encoder (wave per row, 4 rows/wave) ----------------
__global__ __launch_bounds__(256) void k1_enc_lane(
    const float* __restrict__ x, const float* __restrict__ W, const float* __restrict__ b,
    const float* __restrict__ v_sp, u16* __restrict__ e_out, float* __restrict__ a_s)
{
  __shared__ float sW[12*64];
  __shared__ float sb[64];
  __shared__ float sv[256];
  for(int i=threadIdx.x;i<12*64;i+=256) sW[i]=W[i];
  if(threadIdx.x<64) sb[threadIdx.x]=b[threadIdx.x];
  sv[threadIdx.x]=v_sp[threadIdx.x];
  __syncthreads();
  int wave=threadIdx.x>>6, lane=threadIdx.x&63;
  int base = blockIdx.x*16 + wave*4;
  for(int it=0;it<4;it++){
    int row = base+it;
    const float* xr = x + (size_t)row*12;
    float acc = sb[lane];
#pragma unroll
    for(int k=0;k<12;k++) acc += xr[k]*sW[k*64+lane];
    float e = fmaxf(acc,0.f);
    e_out[(size_t)row*64+lane] = f2bf(e);
#pragma unroll
    for(int h=0;h<4;h++){
      float s0 = wsum(e*sv[h*64+lane]);
      if(lane==h) a_s[(size_t)row*4+h]=s0;
    }
  }
}

// ---------------- K2: intersection encoder ----------------
__global__ __launch_bounds__(256) void k2_enc_int(
    const float* __restrict__ x, const float* __restrict__ W, const float* __restrict__ b,
    const float* __restrict__ v_dp, const float* __restrict__ v_sa, const float* __restrict__ v_da,
    const float* __restrict__ h0,
    u16* __restrict__ e_out, float* __restrict__ a_dp, float* __restrict__ a_sa,
    float* __restrict__ a_da, u16* __restrict__ inter320)
{
  __shared__ float sW[16*64];
  __shared__ float sb[64];
  __shared__ float sv[3*256];
  for(int i=threadIdx.x;i<16*64;i+=256) sW[i]=W[i];
  if(threadIdx.x<64) sb[threadIdx.x]=b[threadIdx.x];
  { int i=threadIdx.x; sv[i]=v_dp[i]; sv[256+i]=v_sa[i]; sv[512+i]=v_da[i]; }
  __syncthreads();
  int wave=threadIdx.x>>6, lane=threadIdx.x&63;
  int base = blockIdx.x*16 + wave*4;
  for(int it=0;it<4;it++){
    int row = base+it;
    const float* xr = x + (size_t)row*16;
    float acc = sb[lane];
#pragma unroll
    for(int k=0;k<16;k++) acc += xr[k]*sW[k*64+lane];
    float e = fmaxf(acc,0.f);
    e_out[(size_t)row*64+lane] = f2bf(e);
    inter320[(size_t)row*320 + 256 + lane] = f2bf(h0[(size_t)row*64+lane]);
#pragma unroll
    for(int h=0;h<4;h++){
      float s0 = wsum(e*sv[h*64+lane]);
      if(lane==h) a_dp[(size_t)row*4+h]=s0;
      float s1 = wsum(e*sv[256+h*64+lane]);
      if(lane==h) a_sa[(size_t)row*4+h]=s1;
      float s2 = wsum(e*sv[512+h*64+lane]);
      if(lane==h) a_da[(size_t)row*4+h]=s2;
    }
  }
}

// ---------------- K3: degree histogram ----------------
__global__ __launch_bounds__(256) void k3_hist(
    const int* __restrict__ dst_po, const int* __restrict__ dst_adj, int* __restrict__ cnt)
{
  int i = blockIdx.x*256 + threadIdx.x;
  if(i < EPO) atomicAdd(&cnt[dst_po[i]], 1);
  else if(i < EPO+EADJ) atomicAdd(&cnt[NI + dst_adj[i-EPO]], 1);
}

// ---------------- K4: 3-phase exclusive scan (per array y=0 po, y=1 adj) ----------------
__global__ __launch_bounds__(1024) void k4a_scan(
    const int* __restrict__ cnt, int* __restrict__ offA, int* __restrict__ bsum)
{
  __shared__ int s[1024];
  int y = blockIdx.y;
  int i = blockIdx.x*1024 + threadIdx.x;
  int v = (i<NI) ? cnt[y*NI+i] : 0;
  s[threadIdx.x]=v;
  __syncthreads();
  for(int o=1;o<1024;o<<=1){
    int t = (threadIdx.x>=o) ? s[threadIdx.x-o] : 0;
    __syncthreads();
    s[threadIdx.x] += t;
    __syncthreads();
  }
  if(i<NI) offA[y*NI+i] = s[threadIdx.x]-v;
  if(threadIdx.x==1023) bsum[y*64+blockIdx.x] = s[1023];
}

__global__ __launch_bounds__(128) void k4b_scanb(int* __restrict__ bsum)
{
  int y = threadIdx.x>>6, lane = threadIdx.x&63;
  int v = (lane<49) ? bsum[y*64+lane] : 0;
  int orig = v;
#pragma unroll
  for(int o=1;o<64;o<<=1){
    int t = __shfl_up(v,o,64);
    if(lane>=o) v += t;
  }
  if(lane<49) bsum[y*64+lane] = v-orig;
}

__global__ __launch_bounds__(1024) void k4c_add(
    int* __restrict__ offA, int* __restrict__ cur, const int* __restrict__ bsum)
{
  int y = blockIdx.y;
  int i = blockIdx.x*1024 + threadIdx.x;
  if(i<NI){
    int o = offA[y*NI+i] + bsum[y*64+blockIdx.x];
    offA[y*NI+i]=o;
    cur[y*NI+i]=o;
  }
}

// ---------------- K5: scatter edge ids into CSR ----------------
__global__ __launch_bounds__(256) void k5_scatter(
    const int* __restrict__ dst_po, const int* __restrict__ dst_adj,
    int* __restrict__ cur, int* __restrict__ eidx_po, int* __restrict__ eidx_adj)
{
  int i = blockIdx.x*256 + threadIdx.x;
  if(i < EPO){
    int d = dst_po[i];
    int p = atomicAdd(&cur[d],1);
    eidx_po[p] = i;
  } else if(i < EPO+EADJ){
    int e = i-EPO;
    int d = dst_adj[e];
    int p = atomicAdd(&cur[NI+d],1);
    eidx_adj[p] = e;
  }
}

// ---------------- K6: per-dst online-softmax aggregation (wave per dst) ----------------
__global__ __launch_bounds__(256) void k6_agg(
    const int* __restrict__ off, const int* __restrict__ cnt,
    const int* __restrict__ eidx, const int* __restrict__ src,
    const float* __restrict__ a_s, const float* __restrict__ a_d,
    const u16* __restrict__ emat, u16* __restrict__ agg, int colofs)
{
  int wave=threadIdx.x>>6, lane=threadIdx.x&63;
  int d = blockIdx.x*4 + wave;
  if(d>=NI) return;
  const float4 ad = *(const float4*)(a_d + (size_t)d*4);
  float m[4], l[4], c[4];
#pragma unroll
  for(int h=0;h<4;h++){ m[h]=-INFINITY; l[h]=0.f; c[h]=0.f; }
  int beg = off[d], n = cnt[d];
  for(int t=0;t<n;t++){
    int e = eidx[beg+t];
    int s = src[e];
    const float4 as = *(const float4*)(a_s + (size_t)s*4);
    float ev = bf2f(emat[(size_t)s*64+lane]);
    float al[4] = {as.x+ad.x, as.y+ad.y, as.z+ad.z, as.w+ad.w};
#pragma unroll
    for(int h=0;h<4;h++){
      float a2 = al[h] > 0.f ? al[h] : 0.2f*al[h];
      float mn = fmaxf(m[h], a2);
      float sc = __expf(m[h]-mn);
      float pe = __expf(a2-mn);
      l[h] = l[h]*sc + pe;
      c[h] = c[h]*sc + pe*ev;
      m[h] = mn;
    }
  }
  size_t ob = (size_t)d*512 + (size_t)colofs + lane;
#pragma unroll
  for(int h=0;h<4;h++)
    agg[ob + h*64] = f2bf(n>0 ? c[h]/l[h] : 0.f);
}

// ---------------- GEMM: C[N,M] = A[N,K](bf16) @ B (BT[M,K] bf16), 64x64 tile, BK=32 ----------------
// MODE 0: C f32 = acc + bias      MODE 1: C bf16 = relu(acc + bias)
template<int MODE>
__global__ __launch_bounds__(256) void gemm_bf16(
    const u16* __restrict__ A, const u16* __restrict__ BT, int K,
    void* __restrict__ Cv, int ldc, const float* __restrict__ bias, int N)
{
  __shared__ u16 As[64][40];
  __shared__ u16 Bs[64][40];
  int tid=threadIdx.x, wave=tid>>6, lane=tid&63;
  int row0 = blockIdx.x*64, col0 = blockIdx.y*64;
  int ar = tid>>2, aseg = tid&3;
  int r = lane&15, q = lane>>4;
  f32x4 acc0={0,0,0,0}, acc1={0,0,0,0}, acc2={0,0,0,0}, acc3={0,0,0,0};
  for(int k0=0;k0<K;k0+=32){
    uint4 av = {0,0,0,0};
    int arow = row0+ar;
    if(arow < N) av = *(const uint4*)(A + (size_t)arow*K + k0 + aseg*8);
    uint4 bv = *(const uint4*)(BT + (size_t)(col0+ar)*K + k0 + aseg*8);
    __syncthreads();
    *(uint4*)&As[ar][aseg*8] = av;
    *(uint4*)&Bs[ar][aseg*8] = bv;
    __syncthreads();
    bf16x8 af = *(const bf16x8*)&As[wave*16 + r][q*8];
    bf16x8 b0 = *(const bf16x8*)&Bs[ 0 + r][q*8];
    bf16x8 b1 = *(const bf16x8*)&Bs[16 + r][q*8];
    bf16x8 b2 = *(const bf16x8*)&Bs[32 + r][q*8];
    bf16x8 b3 = *(const bf16x8*)&Bs[48 + r][q*8];
    acc0 = __builtin_amdgcn_mfma_f32_16x16x32_bf16(af,b0,acc0,0,0,0);
    acc1 = __builtin_amdgcn_mfma_f32_16x16x32_bf16(af,b1,acc1,0,0,0);
    acc2 = __builtin_amdgcn_mfma_f32_16x16x32_bf16(af,b2,acc2,0,0,0);
    acc3 = __builtin_amdgcn_mfma_f32_16x16x32_bf16(af,b3,acc3,0,0,0);
  }
  int crow_base = row0 + wave*16 + q*4;
#pragma unroll
  for(int t2=0;t2<4;t2++){
    f32x4 a = (t2==0)?acc0 : (t2==1)?acc1 : (t2==2)?acc2 : acc3;
    int col = col0 + t2*16 + r;
    float bcol = bias[col];
#pragma unroll
    for(int rr=0;rr<4;rr++){
      int row = crow_base + rr;
      if(row < N){
        float v = a[rr] + bcol;
        if(MODE==1) ((u16*)Cv)[(size_t)row*ldc + col] = f2bf(fmaxf(v,0.f));
        else        ((float*)Cv)[(size_t)row*ldc + col] = v;
      }
    }
  }
}

// ---------------- K10: GRU gates + h_new + logits/value ----------------
__global__ __launch_bounds__(256) void k10_gates(
    const float* __restrict__ gmat, const float* __restrict__ h0,
    const float* __restrict__ Wpi, const float* __restrict__ bpi,
    const float* __restrict__ Wv, const float* __restrict__ bvp,
    float* __restrict__ out)
{
  __shared__ float sWpi[512];
  __shared__ float sWv[64];
  __shared__ float sbpi[8];
  __shared__ float sbv[1];
  for(int i=threadIdx.x;i<512;i+=256) sWpi[i]=Wpi[i];
  if(threadIdx.x<64) sWv[threadIdx.x]=Wv[threadIdx.x];
  if(threadIdx.x<8) sbpi[threadIdx.x]=bpi[threadIdx.x];
  if(threadIdx.x==8) sbv[0]=bvp[0];
  __syncthreads();
  int wave=threadIdx.x>>6, lane=threadIdx.x&63;
  int row = blockIdx.x*4 + wave;
  const float* g = gmat + (size_t)row*256;
  float g0=g[lane], g1=g[64+lane], g2=g[128+lane], g3=g[192+lane];
  float h0v = h0[(size_t)row*64+lane];
  float rr = 1.f/(1.f+__expf(-g0));
  float zz = 1.f/(1.f+__expf(-g1));
  float nn = tanhf(g2 + rr*g3);
  float h = (1.f-zz)*nn + zz*h0v;
  out[450000 + (size_t)row*64 + lane] = h;
  float pk[8];
#pragma unroll
  for(int k2=0;k2<8;k2++) pk[k2] = h*sWpi[lane*8+k2];
  float pv = h*sWv[lane];
#pragma unroll
  for(int o=32;o>0;o>>=1){
#pragma unroll
    for(int k2=0;k2<8;k2++) pk[k2] += __shfl_xor(pk[k2],o,64);
    pv += __shfl_xor(pv,o,64);
  }
  if(lane==0){
#pragma unroll
    for(int k2=0;k2<8;k2++) out[(size_t)row*8+k2] = pk[k2]+sbpi[k2];
    out[400000+row] = pv + sbv[0];
  }
}

extern "C" void kernel_launch(void* const* d_in, const int* in_sizes, int n_in,
                              void* d_out, int out_size, void* d_ws, size_t ws_size,
                              hipStream_t stream) {
  const float* x_int      = (const float*)d_in[0];
  const float* x_lane     = (const float*)d_in[1];
  const float* h0         = (const float*)d_in[2];
  const float* enc_int_W  = (const float*)d_in[3];
  const float* enc_int_b  = (const float*)d_in[4];
  const float* enc_lane_W = (const float*)d_in[5];
  const float* enc_lane_b = (const float*)d_in[6];
  const float* Wsrc_po    = (const float*)d_in[7];
  const float* Wdst_po    = (const float*)d_in[8];
  const float* att_src_po = (const float*)d_in[9];
  const float* att_dst_po = (const float*)d_in[10];
  const float* bias_po    = (const float*)d_in[11];
  const float* Wsrc_adj   = (const float*)d_in[12];
  const float* Wdst_adj   = (const float*)d_in[13];
  const float* att_src_adj= (const float*)d_in[14];
  const float* att_dst_adj= (const float*)d_in[15];
  const float* bias_adj   = (const float*)d_in[16];
  const float* gru_W_ih   = (const float*)d_in[17];
  const float* gru_W_hh   = (const float*)d_in[18];
  const float* gru_b_ih   = (const float*)d_in[19];
  const float* gru_b_hh   = (const float*)d_in[20];
  const float* W_pi       = (const float*)d_in[21];
  const float* b_pi       = (const float*)d_in[22];
  const float* W_v        = (const float*)d_in[23];
  const float* b_v        = (const float*)d_in[24];
  const int* src_po  = (const int*)d_in[25];
  const int* dst_po  = (const int*)d_in[26];
  const int* src_adj = (const int*)d_in[27];
  const int* dst_adj = (const int*)d_in[28];
  float* out = (float*)d_out;

  char* w = (char*)d_ws;
  size_t ofs = 0;
  auto alloc = [&](size_t bytes)->char*{
    char* p = w + ofs;
    ofs = (ofs + bytes + 255) & ~(size_t)255;
    return p;
  };
  u16*  e_lane   = (u16*)alloc((size_t)NL*64*2);   // 51.2 MB; aliased as gmat (f32 NI*256) later
  float* gmat    = (float*)e_lane;                 // NI*256*4 == NL*64*2 exactly
  u16*  e_int    = (u16*)alloc((size_t)NI*64*2);
  float* a_s_po  = (float*)alloc((size_t)NL*4*4);
  float* a_d_po  = (float*)alloc((size_t)NI*4*4);
  float* a_s_adj = (float*)alloc((size_t)NI*4*4);
  float* a_d_adj = (float*)alloc((size_t)NI*4*4);
  int*  cnt      = (int*)alloc((size_t)2*NI*4);
  int*  offA     = (int*)alloc((size_t)2*NI*4);
  int*  cur      = (int*)alloc((size_t)2*NI*4);
  int*  eidx_po  = (int*)alloc((size_t)EPO*4);
  int*  eidx_adj = (int*)alloc((size_t)EADJ*4);
  int*  bsum     = (int*)alloc(2*64*4);
  u16*  agg      = (u16*)alloc((size_t)NI*512*2);
  u16*  inter320 = (u16*)alloc((size_t)NI*320*2);
  u16*  WbigT    = (u16*)alloc(256*512*2);
  u16*  B2T      = (u16*)alloc(256*320*2);
  float* v4      = (float*)alloc(4*256*4);
  float* bias_comb = (float*)alloc(256*4);
  float* bias2   = (float*)alloc(256*4);
  (void)ws_size; (void)n_in; (void)in_sizes; (void)out_size;

  // zero counts
  kz<<<(2*NI+255)/256, 256, 0, stream>>>(cnt, 2*NI);
  // weight prep
  k0_prep<<<256, 256, 0, stream>>>(
      Wsrc_po, att_src_po, Wdst_po, att_dst_po,
      Wsrc_adj, att_src_adj, Wdst_adj, att_dst_adj,
      gru_W_ih, gru_W_hh, bias_po, bias_adj, gru_b_ih, gru_b_hh,
      v4, WbigT, B2T, bias_comb, bias2);
  // encoders
  k1_enc_lane<<<NL/16, 256, 0, stream>>>(x_lane, enc_lane_W, enc_lane_b,
      v4 + 0, e_lane, a_s_po);
  k2_enc_int<<<NI/16, 256, 0, stream>>>(x_int, enc_int_W, enc_int_b,
      v4 + 256, v4 + 512, v4 + 768, h0,
      e_int, a_d_po, a_s_adj, a_d_adj, inter320);
  // CSR build
  k3_hist<<<(EPO+EADJ+255)/256, 256, 0, stream>>>(dst_po, dst_adj, cnt);
  k4a_scan<<<dim3(49,2), 1024, 0, stream>>>(cnt, offA, bsum);
  k4b_scanb<<<1, 128, 0, stream>>>(bsum);
  k4c_add<<<dim3(49,2), 1024, 0, stream>>>(offA, cur, bsum);
  k5_scatter<<<(EPO+EADJ+255)/256, 256, 0, stream>>>(dst_po, dst_adj, cur, eidx_po, eidx_adj);
  // edge aggregation (online softmax), po then adj
  k6_agg<<<(NI+3)/4, 256, 0, stream>>>(offA,      cnt,      eidx_po,  src_po,
      a_s_po,  a_d_po,  e_lane, agg, 0);
  k6_agg<<<(NI+3)/4, 256, 0, stream>>>(offA+NI,   cnt+NI,   eidx_adj, src_adj,
      a_s_adj, a_d_adj, e_int,  agg, 256);
  // projection GEMM: inter = relu(agg @ W_big + bias_comb)  -> bf16, ldc=320 (cols 0..255)
  gemm_bf16<1><<<dim3((NI+63)/64, 4), 256, 0, stream>>>(agg, WbigT, 512, inter320, 320, bias_comb, NI);
  // GRU GEMM: gmat = [inter|h0] @ B2 + bias2  -> f32 [NI,256]
  gemm_bf16<0><<<dim3((NI+63)/64, 4), 256, 0, stream>>>(inter320, B2T, 320, gmat, 256, bias2, NI);
  // gates + outputs
  k10_gates<<<NI/4, 256, 0, stream>>>(gmat, h0, W_pi, b_pi, W_v, b_v, out);
}

// Round 2
// 458.889 us; speedup vs baseline: 1.3056x; 1.3056x over previous
//
#include <hip/hip_runtime.h>

#define NI 50000
#define NL 400000
#define EPO 400000
#define EADJ 200000

typedef unsigned int u32;
typedef unsigned short u16;
typedef short bf16x8 __attribute__((ext_vector_type(8)));
typedef float f32x4 __attribute__((ext_vector_type(4)));

__device__ __forceinline__ float bf2f(u16 h){ return __uint_as_float(((u32)h)<<16); }
__device__ __forceinline__ u16 f2bf(float f){
  u32 u = __float_as_uint(f);
  u += 0x7FFFu + ((u>>16)&1u);
  return (u16)(u>>16);
}
__device__ __forceinline__ u32 pack2(float a, float b){
  return (u32)f2bf(a) | ((u32)f2bf(b)<<16);
}

// ---------------- K_zero ----------------
__global__ __launch_bounds__(256) void kz(int* __restrict__ p, int n){
  int i = blockIdx.x*256 + threadIdx.x;
  if(i<n) p[i]=0;
}

// ---------------- K0: weight prep (unchanged) ----------------
__global__ __launch_bounds__(256) void k0_prep(
    const float* __restrict__ Wsrc_po, const float* __restrict__ att_src_po,
    const float* __restrict__ Wdst_po, const float* __restrict__ att_dst_po,
    const float* __restrict__ Wsrc_adj, const float* __restrict__ att_src_adj,
    const float* __restrict__ Wdst_adj, const float* __restrict__ att_dst_adj,
    const float* __restrict__ W_ih, const float* __restrict__ W_hh,
    const float* __restrict__ bias_po, const float* __restrict__ bias_adj,
    const float* __restrict__ b_ih, const float* __restrict__ b_hh,
    float* __restrict__ v4, u16* __restrict__ WbigT, u16* __restrict__ B2T,
    float* __restrict__ bias_comb, float* __restrict__ bias2)
{
  const int T0 = 1024, T1 = 256*512, T2 = 256*320;
  int total = T0 + T1 + T2 + 256 + 256;
  for(int t = blockIdx.x*256 + threadIdx.x; t < total; t += gridDim.x*256){
    if(t < T0){
      int which = t>>8, hc = t&255, h = hc>>6, c = hc&63;
      const float *W, *att;
      if(which==0){ W=Wsrc_po;  att=att_src_po; }
      else if(which==1){ W=Wdst_po;  att=att_dst_po; }
      else if(which==2){ W=Wsrc_adj; att=att_src_adj; }
      else { W=Wdst_adj; att=att_dst_adj; }
      float s=0.f;
      for(int j=0;j<64;j++) s += W[c*256 + h*64 + j]*att[h*64+j];
      v4[which*256 + hc] = s;
    } else if(t < T0 + T1){
      int i = t - T0; int m = i>>9, k = i&511;
      float val = 0.f;
      if(k < 256){ if((k>>6)==(m>>6)) val = Wsrc_po[(k&63)*256 + m]; }
      else { int k2=k-256; if((k2>>6)==(m>>6)) val = Wsrc_adj[(k2&63)*256 + m]; }
      WbigT[m*512+k] = f2bf(val);
    } else if(t < T0 + T1 + T2){
      int i = t - (T0+T1); int m = i/320, k = i - m*320;
      float val = 0.f;
      if(k < 256){ if(m<192) val = W_ih[m*256+k]; }
      else { int kk=k-256;
        if(m<128) val = W_hh[m*64+kk];
        else if(m>=192) val = W_hh[(m-64)*64+kk];
      }
      B2T[m*320+k] = f2bf(val);
    } else if(t < T0 + T1 + T2 + 256){
      int m = t - (T0+T1+T2);
      bias_comb[m] = bias_po[m] + bias_adj[m];
    } else {
      int m = t - (T0+T1+T2+256);
      float v;
      if(m<128) v = b_ih[m] + b_hh[m];
      else if(m<192) v = b_ih[m];
      else v = b_hh[m-64];
      bias2[m] = v;
    }
  }
}

// ---------------- K1 v2: lane encoder, thread-per-row + LDS transpose staging ----------------
__global__ __launch_bounds__(256) void k1_enc_lane(
    const float* __restrict__ x, const float* __restrict__ W, const float* __restrict__ b,
    const float* __restrict__ v_sp, u16* __restrict__ e_out, float* __restrict__ a_s)
{
  __shared__ float sW[12*64];
  __shared__ float sb[64];
  __shared__ float sv[256];
  __shared__ uint4 st4[8][256];   // 32KB staging: [colgroup][localrow]
  int t = threadIdx.x;
  for(int i=t;i<12*64;i+=256) sW[i]=W[i];
  if(t<64) sb[t]=b[t];
  sv[t]=v_sp[t];
  __syncthreads();
  int row = blockIdx.x*256 + t;
  float xv[12];
  if(row < NL){
    const float4* xp = (const float4*)(x + (size_t)row*12);
    float4 x0 = xp[0], x1 = xp[1], x2 = xp[2];
    xv[0]=x0.x; xv[1]=x0.y; xv[2]=x0.z; xv[3]=x0.w;
    xv[4]=x1.x; xv[5]=x1.y; xv[6]=x1.z; xv[7]=x1.w;
    xv[8]=x2.x; xv[9]=x2.y; xv[10]=x2.z; xv[11]=x2.w;
  } else {
#pragma unroll
    for(int k=0;k<12;k++) xv[k]=0.f;
  }
  float as0=0.f, as1=0.f, as2=0.f, as3=0.f;
#pragma unroll
  for(int c8=0;c8<8;c8++){
    float acc[8];
#pragma unroll
    for(int j=0;j<8;j++) acc[j]=sb[c8*8+j];
#pragma unroll
    for(int k=0;k<12;k++){
      float xk = xv[k];
#pragma unroll
      for(int j=0;j<8;j++) acc[j] += xk*sW[k*64 + c8*8 + j];
    }
    float e[8];
#pragma unroll
    for(int j=0;j<8;j++){
      e[j] = fmaxf(acc[j], 0.f);
      int c = c8*8+j;
      as0 += e[j]*sv[c];
      as1 += e[j]*sv[64+c];
      as2 += e[j]*sv[128+c];
      as3 += e[j]*sv[192+c];
    }
    uint4 P;
    P.x = pack2(e[0],e[1]); P.y = pack2(e[2],e[3]);
    P.z = pack2(e[4],e[5]); P.w = pack2(e[6],e[7]);
    st4[c8][t] = P;
  }
  if(row < NL){
    float4 A; A.x=as0; A.y=as1; A.z=as2; A.w=as3;
    *(float4*)(a_s + (size_t)row*4) = A;
  }
  __syncthreads();
  // coalesced global write: logical uint4 idx = localrow*8 + colgroup
  uint4* outp = (uint4*)e_out + (size_t)blockIdx.x*2048;
  int rowlim = NL - blockIdx.x*256;   // rows valid in this block
#pragma unroll
  for(int i=0;i<8;i++){
    int idx = i*256 + t;
    int r = idx>>3, g = idx&7;
    if(r < rowlim) outp[idx] = st4[g][r];
  }
}

// ---------------- K2 v2: intersection encoder (3 att targets) + h0 copy ----------------
__global__ __launch_bounds__(256) void k2_enc_int(
    const float* __restrict__ x, const float* __restrict__ W, const float* __restrict__ b,
    const float* __restrict__ v_dp, const float* __restrict__ v_sa, const float* __restrict__ v_da,
    const float* __restrict__ h0,
    u16* __restrict__ e_out, float* __restrict__ a_dp, float* __restrict__ a_sa,
    float* __restrict__ a_da, u16* __restrict__ inter320)
{
  __shared__ float sW[16*64];
  __shared__ float sb[64];
  __shared__ float sv[3*256];
  __shared__ uint4 st4[8][256];
  int t = threadIdx.x;
  for(int i=t;i<16*64;i+=256) sW[i]=W[i];
  if(t<64) sb[t]=b[t];
  { sv[t]=v_dp[t]; sv[256+t]=v_sa[t]; sv[512+t]=v_da[t]; }
  __syncthreads();
  int row = blockIdx.x*256 + t;
  float xv[16];
  if(row < NI){
    const float4* xp = (const float4*)(x + (size_t)row*16);
#pragma unroll
    for(int q=0;q<4;q++){
      float4 xq = xp[q];
      xv[q*4]=xq.x; xv[q*4+1]=xq.y; xv[q*4+2]=xq.z; xv[q*4+3]=xq.w;
    }
  } else {
#pragma unroll
    for(int k=0;k<16;k++) xv[k]=0.f;
  }
  float ad0=0,ad1=0,ad2=0,ad3=0, sa0=0,sa1=0,sa2=0,sa3=0, da0=0,da1=0,da2=0,da3=0;
#pragma unroll
  for(int c8=0;c8<8;c8++){
    float acc[8];
#pragma unroll
    for(int j=0;j<8;j++) acc[j]=sb[c8*8+j];
#pragma unroll
    for(int k=0;k<16;k++){
      float xk = xv[k];
#pragma unroll
      for(int j=0;j<8;j++) acc[j] += xk*sW[k*64 + c8*8 + j];
    }
    float e[8];
#pragma unroll
    for(int j=0;j<8;j++){
      e[j] = fmaxf(acc[j], 0.f);
      int c = c8*8+j;
      ad0 += e[j]*sv[c];     ad1 += e[j]*sv[64+c];  ad2 += e[j]*sv[128+c];  ad3 += e[j]*sv[192+c];
      sa0 += e[j]*sv[256+c]; sa1 += e[j]*sv[320+c]; sa2 += e[j]*sv[384+c];  sa3 += e[j]*sv[448+c];
      da0 += e[j]*sv[512+c]; da1 += e[j]*sv[576+c]; da2 += e[j]*sv[640+c];  da3 += e[j]*sv[704+c];
    }
    uint4 P;
    P.x = pack2(e[0],e[1]); P.y = pack2(e[2],e[3]);
    P.z = pack2(e[4],e[5]); P.w = pack2(e[6],e[7]);
    st4[c8][t] = P;
  }
  if(row < NI){
    float4 A;
    A.x=ad0; A.y=ad1; A.z=ad2; A.w=ad3; *(float4*)(a_dp + (size_t)row*4) = A;
    A.x=sa0; A.y=sa1; A.z=sa2; A.w=sa3; *(float4*)(a_sa + (size_t)row*4) = A;
    A.x=da0; A.y=da1; A.z=da2; A.w=da3; *(float4*)(a_da + (size_t)row*4) = A;
  }
  __syncthreads();
  uint4* outp = (uint4*)e_out + (size_t)blockIdx.x*2048;
  int rowlim = NI - blockIdx.x*256;
#pragma unroll
  for(int i=0;i<8;i++){
    int idx = i*256 + t;
    int r = idx>>3, g = idx&7;
    if(r < rowlim) outp[idx] = st4[g][r];
  }
  // h0 -> inter320 columns 256..319 (bf16), wave per 64-row slab
  int wave = t>>6, lane = t&63;
  int rbase = blockIdx.x*256 + wave*64;
  for(int i=0;i<64;i++){
    int rr = rbase+i;
    if(rr < NI)
      inter320[(size_t)rr*320 + 256 + lane] = f2bf(h0[(size_t)rr*64+lane]);
  }
}

// ---------------- K3: degree histogram ----------------
__global__ __launch_bounds__(256) void k3_hist(
    const int* __restrict__ dst_po, const int* __restrict__ dst_adj, int* __restrict__ cnt)
{
  int i = blockIdx.x*256 + threadIdx.x;
  if(i < EPO) atomicAdd(&cnt[dst_po[i]], 1);
  else if(i < EPO+EADJ) atomicAdd(&cnt[NI + dst_adj[i-EPO]], 1);
}

// ---------------- K4: scan ----------------
__global__ __launch_bounds__(1024) void k4a_scan(
    const int* __restrict__ cnt, int* __restrict__ offA, int* __restrict__ bsum)
{
  __shared__ int s[1024];
  int y = blockIdx.y;
  int i = blockIdx.x*1024 + threadIdx.x;
  int v = (i<NI) ? cnt[y*NI+i] : 0;
  s[threadIdx.x]=v;
  __syncthreads();
  for(int o=1;o<1024;o<<=1){
    int t = (threadIdx.x>=o) ? s[threadIdx.x-o] : 0;
    __syncthreads();
    s[threadIdx.x] += t;
    __syncthreads();
  }
  if(i<NI) offA[y*NI+i] = s[threadIdx.x]-v;
  if(threadIdx.x==1023) bsum[y*64+blockIdx.x] = s[1023];
}

__global__ __launch_bounds__(128) void k4b_scanb(int* __restrict__ bsum)
{
  int y = threadIdx.x>>6, lane = threadIdx.x&63;
  int v = (lane<49) ? bsum[y*64+lane] : 0;
  int orig = v;
#pragma unroll
  for(int o=1;o<64;o<<=1){
    int t = __shfl_up(v,o,64);
    if(lane>=o) v += t;
  }
  if(lane<49) bsum[y*64+lane] = v-orig;
}

__global__ __launch_bounds__(1024) void k4c_add(
    int* __restrict__ offA, int* __restrict__ cur, const int* __restrict__ bsum)
{
  int y = blockIdx.y;
  int i = blockIdx.x*1024 + threadIdx.x;
  if(i<NI){
    int o = offA[y*NI+i] + bsum[y*64+blockIdx.x];
    offA[y*NI+i]=o;
    cur[y*NI+i]=o;
  }
}

// ---------------- K5: scatter src ids into CSR ----------------
__global__ __launch_bounds__(256) void k5_scatter(
    const int* __restrict__ src_po, const int* __restrict__ dst_po,
    const int* __restrict__ src_adj, const int* __restrict__ dst_adj,
    int* __restrict__ cur, int* __restrict__ csr_po, int* __restrict__ csr_adj)
{
  int i = blockIdx.x*256 + threadIdx.x;
  if(i < EPO){
    int d = dst_po[i];
    int p = atomicAdd(&cur[d],1);
    csr_po[p] = src_po[i];
  } else if(i < EPO+EADJ){
    int e = i-EPO;
    int d = dst_adj[e];
    int p = atomicAdd(&cur[NI+d],1);
    csr_adj[p] = src_adj[e];
  }
}

// ---------------- K6 v2: merged softmax-aggregation, no online max ----------------
__device__ __forceinline__ void agg_rel(
    int beg, int n, int lane,
    const int* __restrict__ csr, const float* __restrict__ a_s, float4 ad,
    const u16* __restrict__ emat, u16* __restrict__ aggrow)
{
  float l0=0,l1=0,l2=0,l3=0;
  float c0=0,c1=0,c2=0,c3=0;
  for(int base=0;base<n;base+=64){
    int m = n-base; if(m>64) m=64;
    int sv_ = (lane<m) ? csr[beg+base+lane] : 0;
    int t2=0;
    for(; t2+1<m; t2+=2){
      int s0 = __shfl(sv_, t2, 64);
      int s1 = __shfl(sv_, t2+1, 64);
      float4 A0 = *(const float4*)(a_s + (size_t)s0*4);
      float4 A1 = *(const float4*)(a_s + (size_t)s1*4);
      float e0 = bf2f(emat[(size_t)s0*64+lane]);
      float e1 = bf2f(emat[(size_t)s1*64+lane]);
      float x0,x1,x2,x3,p;
      x0=A0.x+ad.x; x1=A0.y+ad.y; x2=A0.z+ad.z; x3=A0.w+ad.w;
      p=__expf(x0>0.f?x0:0.2f*x0); l0+=p; c0+=p*e0;
      p=__expf(x1>0.f?x1:0.2f*x1); l1+=p; c1+=p*e0;
      p=__expf(x2>0.f?x2:0.2f*x2); l2+=p; c2+=p*e0;
      p=__expf(x3>0.f?x3:0.2f*x3); l3+=p; c3+=p*e0;
      x0=A1.x+ad.x; x1=A1.y+ad.y; x2=A1.z+ad.z; x3=A1.w+ad.w;
      p=__expf(x0>0.f?x0:0.2f*x0); l0+=p; c0+=p*e1;
      p=__expf(x1>0.f?x1:0.2f*x1); l1+=p; c1+=p*e1;
      p=__expf(x2>0.f?x2:0.2f*x2); l2+=p; c2+=p*e1;
      p=__expf(x3>0.f?x3:0.2f*x3); l3+=p; c3+=p*e1;
    }
    if(t2<m){
      int s0 = __shfl(sv_, t2, 64);
      float4 A0 = *(const float4*)(a_s + (size_t)s0*4);
      float e0 = bf2f(emat[(size_t)s0*64+lane]);
      float x0,x1,x2,x3,p;
      x0=A0.x+ad.x; x1=A0.y+ad.y; x2=A0.z+ad.z; x3=A0.w+ad.w;
      p=__expf(x0>0.f?x0:0.2f*x0); l0+=p; c0+=p*e0;
      p=__expf(x1>0.f?x1:0.2f*x1); l1+=p; c1+=p*e0;
      p=__expf(x2>0.f?x2:0.2f*x2); l2+=p; c2+=p*e0;
      p=__expf(x3>0.f?x3:0.2f*x3); l3+=p; c3+=p*e0;
    }
  }
  aggrow[lane]       = f2bf(n>0 ? c0/l0 : 0.f);
  aggrow[64+lane]    = f2bf(n>0 ? c1/l1 : 0.f);
  aggrow[128+lane]   = f2bf(n>0 ? c2/l2 : 0.f);
  aggrow[192+lane]   = f2bf(n>0 ? c3/l3 : 0.f);
}

__global__ __launch_bounds__(256) void k6_agg(
    const int* __restrict__ off, const int* __restrict__ cnt,
    const int* __restrict__ csr_po, const int* __restrict__ csr_adj,
    const float* __restrict__ a_s_po, const float* __restrict__ a_d_po,
    const float* __restrict__ a_s_adj, const float* __restrict__ a_d_adj,
    const u16* __restrict__ e_lane, const u16* __restrict__ e_int,
    u16* __restrict__ agg)
{
  int wave=threadIdx.x>>6, lane=threadIdx.x&63;
  int d = blockIdx.x*4 + wave;
  if(d>=NI) return;
  {
    float4 ad = *(const float4*)(a_d_po + (size_t)d*4);
    agg_rel(off[d], cnt[d], lane, csr_po, a_s_po, ad, e_lane, agg + (size_t)d*512);
  }
  {
    float4 ad = *(const float4*)(a_d_adj + (size_t)d*4);
    agg_rel(off[NI+d], cnt[NI+d], lane, csr_adj, a_s_adj, ad, e_int, agg + (size_t)d*512 + 256);
  }
}

// ---------------- GEMM (unchanged) ----------------
template<int MODE>
__global__ __launch_bounds__(256) void gemm_bf16(
    const u16* __restrict__ A, const u16* __restrict__ BT, int K,
    void* __restrict__ Cv, int ldc, const float* __restrict__ bias, int N)
{
  __shared__ u16 As[64][40];
  __shared__ u16 Bs[64][40];
  int tid=threadIdx.x, wave=tid>>6, lane=tid&63;
  int row0 = blockIdx.x*64, col0 = blockIdx.y*64;
  int ar = tid>>2, aseg = tid&3;
  int r = lane&15, q = lane>>4;
  f32x4 acc0={0,0,0,0}, acc1={0,0,0,0}, acc2={0,0,0,0}, acc3={0,0,0,0};
  for(int k0=0;k0<K;k0+=32){
    uint4 av = {0,0,0,0};
    int arow = row0+ar;
    if(arow < N) av = *(const uint4*)(A + (size_t)arow*K + k0 + aseg*8);
    uint4 bv = *(const uint4*)(BT + (size_t)(col0+ar)*K + k0 + aseg*8);
    __syncthreads();
    *(uint4*)&As[ar][aseg*8] = av;
    *(uint4*)&Bs[ar][aseg*8] = bv;
    __syncthreads();
    bf16x8 af = *(const bf16x8*)&As[wave*16 + r][q*8];
    bf16x8 b0 = *(const bf16x8*)&Bs[ 0 + r][q*8];
    bf16x8 b1 = *(const bf16x8*)&Bs[16 + r][q*8];
    bf16x8 b2 = *(const bf16x8*)&Bs[32 + r][q*8];
    bf16x8 b3 = *(const bf16x8*)&Bs[48 + r][q*8];
    acc0 = __builtin_amdgcn_mfma_f32_16x16x32_bf16(af,b0,acc0,0,0,0);
    acc1 = __builtin_amdgcn_mfma_f32_16x16x32_bf16(af,b1,acc1,0,0,0);
    acc2 = __builtin_amdgcn_mfma_f32_16x16x32_bf16(af,b2,acc2,0,0,0);
    acc3 = __builtin_amdgcn_mfma_f32_16x16x32_bf16(af,b3,acc3,0,0,0);
  }
  int crow_base = row0 + wave*16 + q*4;
#pragma unroll
  for(int t2=0;t2<4;t2++){
    f32x4 a = (t2==0)?acc0 : (t2==1)?acc1 : (t2==2)?acc2 : acc3;
    int col = col0 + t2*16 + r;
    float bcol = bias[col];
#pragma unroll
    for(int rr=0;rr<4;rr++){
      int row = crow_base + rr;
      if(row < N){
        float v = a[rr] + bcol;
        if(MODE==1) ((u16*)Cv)[(size_t)row*ldc + col] = f2bf(fmaxf(v,0.f));
        else        ((float*)Cv)[(size_t)row*ldc + col] = v;
      }
    }
  }
}

// ---------------- K10: GRU gates + outputs (unchanged) ----------------
__global__ __launch_bounds__(256) void k10_gates(
    const float* __restrict__ gmat, const float* __restrict__ h0,
    const float* __restrict__ Wpi, const float* __restrict__ bpi,
    const float* __restrict__ Wv, const float* __restrict__ bvp,
    float* __restrict__ out)
{
  __shared__ float sWpi[512];
  __shared__ float sWv[64];
  __shared__ float sbpi[8];
  __shared__ float sbv[1];
  for(int i=threadIdx.x;i<512;i+=256) sWpi[i]=Wpi[i];
  if(threadIdx.x<64) sWv[threadIdx.x]=Wv[threadIdx.x];
  if(threadIdx.x<8) sbpi[threadIdx.x]=bpi[threadIdx.x];
  if(threadIdx.x==8) sbv[0]=bvp[0];
  __syncthreads();
  int wave=threadIdx.x>>6, lane=threadIdx.x&63;
  int row = blockIdx.x*4 + wave;
  const float* g = gmat + (size_t)row*256;
  float g0=g[lane], g1=g[64+lane], g2=g[128+lane], g3=g[192+lane];
  float h0v = h0[(size_t)row*64+lane];
  float rr = 1.f/(1.f+__expf(-g0));
  float zz = 1.f/(1.f+__expf(-g1));
  float nn = tanhf(g2 + rr*g3);
  float h = (1.f-zz)*nn + zz*h0v;
  out[450000 + (size_t)row*64 + lane] = h;
  float pk[8];
#pragma unroll
  for(int k2=0;k2<8;k2++) pk[k2] = h*sWpi[lane*8+k2];
  float pv = h*sWv[lane];
#pragma unroll
  for(int o=32;o>0;o>>=1){
#pragma unroll
    for(int k2=0;k2<8;k2++) pk[k2] += __shfl_xor(pk[k2],o,64);
    pv += __shfl_xor(pv,o,64);
  }
  if(lane==0){
#pragma unroll
    for(int k2=0;k2<8;k2++) out[(size_t)row*8+k2] = pk[k2]+sbpi[k2];
    out[400000+row] = pv + sbv[0];
  }
}

extern "C" void kernel_launch(void* const* d_in, const int* in_sizes, int n_in,
                              void* d_out, int out_size, void* d_ws, size_t ws_size,
                              hipStream_t stream) {
  const float* x_int      = (const float*)d_in[0];
  const float* x_lane     = (const float*)d_in[1];
  const float* h0         = (const float*)d_in[2];
  const float* enc_int_W  = (const float*)d_in[3];
  const float* enc_int_b  = (const float*)d_in[4];
  const float* enc_lane_W = (const float*)d_in[5];
  const float* enc_lane_b = (const float*)d_in[6];
  const float* Wsrc_po    = (const float*)d_in[7];
  const float* Wdst_po    = (const float*)d_in[8];
  const float* att_src_po = (const float*)d_in[9];
  const float* att_dst_po = (const float*)d_in[10];
  const float* bias_po    = (const float*)d_in[11];
  const float* Wsrc_adj   = (const float*)d_in[12];
  const float* Wdst_adj   = (const float*)d_in[13];
  const float* att_src_adj= (const float*)d_in[14];
  const float* att_dst_adj= (const float*)d_in[15];
  const float* bias_adj   = (const float*)d_in[16];
  const float* gru_W_ih   = (const float*)d_in[17];
  const float* gru_W_hh   = (const float*)d_in[18];
  const float* gru_b_ih   = (const float*)d_in[19];
  const float* gru_b_hh   = (const float*)d_in[20];
  const float* W_pi       = (const float*)d_in[21];
  const float* b_pi       = (const float*)d_in[22];
  const float* W_v        = (const float*)d_in[23];
  const float* b_v        = (const float*)d_in[24];
  const int* src_po  = (const int*)d_in[25];
  const int* dst_po  = (const int*)d_in[26];
  const int* src_adj = (const int*)d_in[27];
  const int* dst_adj = (const int*)d_in[28];
  float* out = (float*)d_out;

  char* w = (char*)d_ws;
  size_t ofs = 0;
  auto alloc = [&](size_t bytes)->char*{
    char* p = w + ofs;
    ofs = (ofs + bytes + 255) & ~(size_t)255;
    return p;
  };
  u16*  e_lane   = (u16*)alloc((size_t)NL*64*2);   // aliased as gmat later
  float* gmat    = (float*)e_lane;                 // NI*256*4 == NL*64*2
  u16*  e_int    = (u16*)alloc((size_t)NI*64*2);
  float* a_s_po  = (float*)alloc((size_t)NL*4*4);
  float* a_d_po  = (float*)alloc((size_t)NI*4*4);
  float* a_s_adj = (float*)alloc((size_t)NI*4*4);
  float* a_d_adj = (float*)alloc((size_t)NI*4*4);
  int*  cnt      = (int*)alloc((size_t)2*NI*4);
  int*  offA     = (int*)alloc((size_t)2*NI*4);
  int*  cur      = (int*)alloc((size_t)2*NI*4);
  int*  csr_po   = (int*)alloc((size_t)EPO*4);
  int*  csr_adj  = (int*)alloc((size_t)EADJ*4);
  int*  bsum     = (int*)alloc(2*64*4);
  u16*  agg      = (u16*)alloc((size_t)NI*512*2);
  u16*  inter320 = (u16*)alloc((size_t)NI*320*2);
  u16*  WbigT    = (u16*)alloc(256*512*2);
  u16*  B2T      = (u16*)alloc(256*320*2);
  float* v4      = (float*)alloc(4*256*4);
  float* bias_comb = (float*)alloc(256*4);
  float* bias2   = (float*)alloc(256*4);
  (void)ws_size; (void)n_in; (void)in_sizes; (void)out_size;

  kz<<<(2*NI+255)/256, 256, 0, stream>>>(cnt, 2*NI);
  k0_prep<<<256, 256, 0, stream>>>(
      Wsrc_po, att_src_po, Wdst_po, att_dst_po,
      Wsrc_adj, att_src_adj, Wdst_adj, att_dst_adj,
      gru_W_ih, gru_W_hh, bias_po, bias_adj, gru_b_ih, gru_b_hh,
      v4, WbigT, B2T, bias_comb, bias2);
  k1_enc_lane<<<(NL+255)/256, 256, 0, stream>>>(x_lane, enc_lane_W, enc_lane_b,
      v4 + 0, e_lane, a_s_po);
  k2_enc_int<<<(NI+255)/256, 256, 0, stream>>>(x_int, enc_int_W, enc_int_b,
      v4 + 256, v4 + 512, v4 + 768, h0,
      e_int, a_d_po, a_s_adj, a_d_adj, inter320);
  k3_hist<<<(EPO+EADJ+255)/256, 256, 0, stream>>>(dst_po, dst_adj, cnt);
  k4a_scan<<<dim3(49,2), 1024, 0, stream>>>(cnt, offA, bsum);
  k4b_scanb<<<1, 128, 0, stream>>>(bsum);
  k4c_add<<<dim3(49,2), 1024, 0, stream>>>(offA, cur, bsum);
  k5_scatter<<<(EPO+EADJ+255)/256, 256, 0, stream>>>(src_po, dst_po, src_adj, dst_adj,
      cur, csr_po, csr_adj);
  k6_agg<<<(NI+3)/4, 256, 0, stream>>>(offA, cnt, csr_po, csr_adj,
      a_s_po, a_d_po, a_s_adj, a_d_adj, e_lane, e_int, agg);
  gemm_bf16<1><<<dim3((NI+63)/64, 4), 256, 0, stream>>>(agg, WbigT, 512, inter320, 320, bias_comb, NI);
  gemm_bf16<0><<<dim3((NI+63)/64, 4), 256, 0, stream>>>(inter320, B2T, 320, gmat, 256, bias2, NI);
  k10_gates<<<NI/4, 256, 0, stream>>>(gmat, h0, W_pi, b_pi, W_v, b_v, out);
}

// Round 3
// 428.014 us; speedup vs baseline: 1.3998x; 1.0721x over previous
//
#include <hip/hip_runtime.h>

#define NI 50000
#define NL 400000
#define EPO 400000
#define EADJ 200000

typedef unsigned int u32;
typedef unsigned short u16;
typedef short bf16x8 __attribute__((ext_vector_type(8)));
typedef float f32x4 __attribute__((ext_vector_type(4)));

__device__ __forceinline__ float bf2f(u16 h){ return __uint_as_float(((u32)h)<<16); }
__device__ __forceinline__ u16 f2bf(float f){
  u32 u = __float_as_uint(f);
  u += 0x7FFFu + ((u>>16)&1u);
  return (u16)(u>>16);
}
__device__ __forceinline__ u32 pack2(float a, float b){
  return (u32)f2bf(a) | ((u32)f2bf(b)<<16);
}

// ---------------- K_zero ----------------
__global__ __launch_bounds__(256) void kz(int* __restrict__ p, int n){
  int i = blockIdx.x*256 + threadIdx.x;
  if(i<n) p[i]=0;
}

// ---------------- K0: weight prep ----------------
// v4[which][h*64+c]: att-projection vectors
// WheadT[h][m][k] (4 x 64 x 128 bf16): k<64 -> Wsrc_po[k][h*64+m], k>=64 -> Wsrc_adj[k-64][h*64+m]
// B2T[m][k] (256x320 bf16): [inter|h0] -> [r_sum z_sum i_n h_n]
__global__ __launch_bounds__(256) void k0_prep(
    const float* __restrict__ Wsrc_po, const float* __restrict__ att_src_po,
    const float* __restrict__ Wdst_po, const float* __restrict__ att_dst_po,
    const float* __restrict__ Wsrc_adj, const float* __restrict__ att_src_adj,
    const float* __restrict__ Wdst_adj, const float* __restrict__ att_dst_adj,
    const float* __restrict__ W_ih, const float* __restrict__ W_hh,
    const float* __restrict__ bias_po, const float* __restrict__ bias_adj,
    const float* __restrict__ b_ih, const float* __restrict__ b_hh,
    float* __restrict__ v4, u16* __restrict__ WheadT, u16* __restrict__ B2T,
    float* __restrict__ bias_comb, float* __restrict__ bias2)
{
  const int T0 = 1024, T1 = 4*64*128, T2 = 256*320;
  int total = T0 + T1 + T2 + 256 + 256;
  for(int t = blockIdx.x*256 + threadIdx.x; t < total; t += gridDim.x*256){
    if(t < T0){
      int which = t>>8, hc = t&255, h = hc>>6, c = hc&63;
      const float *W, *att;
      if(which==0){ W=Wsrc_po;  att=att_src_po; }
      else if(which==1){ W=Wdst_po;  att=att_dst_po; }
      else if(which==2){ W=Wsrc_adj; att=att_src_adj; }
      else { W=Wdst_adj; att=att_dst_adj; }
      float s=0.f;
      for(int j=0;j<64;j++) s += W[c*256 + h*64 + j]*att[h*64+j];
      v4[which*256 + hc] = s;
    } else if(t < T0 + T1){
      int i = t - T0; int h = i>>13, rem = i&8191, m = rem>>7, k = rem&127;
      float val = (k<64) ? Wsrc_po[k*256 + h*64 + m]
                         : Wsrc_adj[(k-64)*256 + h*64 + m];
      WheadT[i] = f2bf(val);
    } else if(t < T0 + T1 + T2){
      int i = t - (T0+T1); int m = i/320, k = i - m*320;
      float val = 0.f;
      if(k < 256){ if(m<192) val = W_ih[m*256+k]; }
      else { int kk=k-256;
        if(m<128) val = W_hh[m*64+kk];
        else if(m>=192) val = W_hh[(m-64)*64+kk];
      }
      B2T[m*320+k] = f2bf(val);
    } else if(t < T0 + T1 + T2 + 256){
      int m = t - (T0+T1+T2);
      bias_comb[m] = bias_po[m] + bias_adj[m];
    } else {
      int m = t - (T0+T1+T2+256);
      float v;
      if(m<128) v = b_ih[m] + b_hh[m];
      else if(m<192) v = b_ih[m];
      else v = b_hh[m-64];
      bias2[m] = v;
    }
  }
}

// ---------------- K1: lane encoder, thread-per-row + LDS transpose staging ----------------
__global__ __launch_bounds__(256) void k1_enc_lane(
    const float* __restrict__ x, const float* __restrict__ W, const float* __restrict__ b,
    const float* __restrict__ v_sp, u16* __restrict__ e_out, float* __restrict__ a_s)
{
  __shared__ float sW[12*64];
  __shared__ float sb[64];
  __shared__ float sv[256];
  __shared__ uint4 st4[8][256];
  int t = threadIdx.x;
  for(int i=t;i<12*64;i+=256) sW[i]=W[i];
  if(t<64) sb[t]=b[t];
  sv[t]=v_sp[t];
  __syncthreads();
  int row = blockIdx.x*256 + t;
  float xv[12];
  if(row < NL){
    const float4* xp = (const float4*)(x + (size_t)row*12);
    float4 x0 = xp[0], x1 = xp[1], x2 = xp[2];
    xv[0]=x0.x; xv[1]=x0.y; xv[2]=x0.z; xv[3]=x0.w;
    xv[4]=x1.x; xv[5]=x1.y; xv[6]=x1.z; xv[7]=x1.w;
    xv[8]=x2.x; xv[9]=x2.y; xv[10]=x2.z; xv[11]=x2.w;
  } else {
#pragma unroll
    for(int k=0;k<12;k++) xv[k]=0.f;
  }
  float as0=0.f, as1=0.f, as2=0.f, as3=0.f;
#pragma unroll
  for(int c8=0;c8<8;c8++){
    float acc[8];
#pragma unroll
    for(int j=0;j<8;j++) acc[j]=sb[c8*8+j];
#pragma unroll
    for(int k=0;k<12;k++){
      float xk = xv[k];
#pragma unroll
      for(int j=0;j<8;j++) acc[j] += xk*sW[k*64 + c8*8 + j];
    }
    float e[8];
#pragma unroll
    for(int j=0;j<8;j++){
      e[j] = fmaxf(acc[j], 0.f);
      int c = c8*8+j;
      as0 += e[j]*sv[c];
      as1 += e[j]*sv[64+c];
      as2 += e[j]*sv[128+c];
      as3 += e[j]*sv[192+c];
    }
    uint4 P;
    P.x = pack2(e[0],e[1]); P.y = pack2(e[2],e[3]);
    P.z = pack2(e[4],e[5]); P.w = pack2(e[6],e[7]);
    st4[c8][t] = P;
  }
  if(row < NL){
    float4 A; A.x=as0; A.y=as1; A.z=as2; A.w=as3;
    *(float4*)(a_s + (size_t)row*4) = A;
  }
  __syncthreads();
  uint4* outp = (uint4*)e_out + (size_t)blockIdx.x*2048;
  int rowlim = NL - blockIdx.x*256;
#pragma unroll
  for(int i=0;i<8;i++){
    int idx = i*256 + t;
    int r = idx>>3, g = idx&7;
    if(r < rowlim) outp[idx] = st4[g][r];
  }
}

// ---------------- K2: intersection encoder + h0 copy ----------------
__global__ __launch_bounds__(256) void k2_enc_int(
    const float* __restrict__ x, const float* __restrict__ W, const float* __restrict__ b,
    const float* __restrict__ v_dp, const float* __restrict__ v_sa, const float* __restrict__ v_da,
    const float* __restrict__ h0,
    u16* __restrict__ e_out, float* __restrict__ a_dp, float* __restrict__ a_sa,
    float* __restrict__ a_da, u16* __restrict__ inter320)
{
  __shared__ float sW[16*64];
  __shared__ float sb[64];
  __shared__ float sv[3*256];
  __shared__ uint4 st4[8][256];
  int t = threadIdx.x;
  for(int i=t;i<16*64;i+=256) sW[i]=W[i];
  if(t<64) sb[t]=b[t];
  { sv[t]=v_dp[t]; sv[256+t]=v_sa[t]; sv[512+t]=v_da[t]; }
  __syncthreads();
  int row = blockIdx.x*256 + t;
  float xv[16];
  if(row < NI){
    const float4* xp = (const float4*)(x + (size_t)row*16);
#pragma unroll
    for(int q=0;q<4;q++){
      float4 xq = xp[q];
      xv[q*4]=xq.x; xv[q*4+1]=xq.y; xv[q*4+2]=xq.z; xv[q*4+3]=xq.w;
    }
  } else {
#pragma unroll
    for(int k=0;k<16;k++) xv[k]=0.f;
  }
  float ad0=0,ad1=0,ad2=0,ad3=0, sa0=0,sa1=0,sa2=0,sa3=0, da0=0,da1=0,da2=0,da3=0;
#pragma unroll
  for(int c8=0;c8<8;c8++){
    float acc[8];
#pragma unroll
    for(int j=0;j<8;j++) acc[j]=sb[c8*8+j];
#pragma unroll
    for(int k=0;k<16;k++){
      float xk = xv[k];
#pragma unroll
      for(int j=0;j<8;j++) acc[j] += xk*sW[k*64 + c8*8 + j];
    }
    float e[8];
#pragma unroll
    for(int j=0;j<8;j++){
      e[j] = fmaxf(acc[j], 0.f);
      int c = c8*8+j;
      ad0 += e[j]*sv[c];     ad1 += e[j]*sv[64+c];  ad2 += e[j]*sv[128+c];  ad3 += e[j]*sv[192+c];
      sa0 += e[j]*sv[256+c]; sa1 += e[j]*sv[320+c]; sa2 += e[j]*sv[384+c];  sa3 += e[j]*sv[448+c];
      da0 += e[j]*sv[512+c]; da1 += e[j]*sv[576+c]; da2 += e[j]*sv[640+c];  da3 += e[j]*sv[704+c];
    }
    uint4 P;
    P.x = pack2(e[0],e[1]); P.y = pack2(e[2],e[3]);
    P.z = pack2(e[4],e[5]); P.w = pack2(e[6],e[7]);
    st4[c8][t] = P;
  }
  if(row < NI){
    float4 A;
    A.x=ad0; A.y=ad1; A.z=ad2; A.w=ad3; *(float4*)(a_dp + (size_t)row*4) = A;
    A.x=sa0; A.y=sa1; A.z=sa2; A.w=sa3; *(float4*)(a_sa + (size_t)row*4) = A;
    A.x=da0; A.y=da1; A.z=da2; A.w=da3; *(float4*)(a_da + (size_t)row*4) = A;
  }
  __syncthreads();
  uint4* outp = (uint4*)e_out + (size_t)blockIdx.x*2048;
  int rowlim = NI - blockIdx.x*256;
#pragma unroll
  for(int i=0;i<8;i++){
    int idx = i*256 + t;
    int r = idx>>3, g = idx&7;
    if(r < rowlim) outp[idx] = st4[g][r];
  }
  int wave = t>>6, lane = t&63;
  int rbase = blockIdx.x*256 + wave*64;
  for(int i=0;i<64;i++){
    int rr = rbase+i;
    if(rr < NI)
      inter320[(size_t)rr*320 + 256 + lane] = f2bf(h0[(size_t)rr*64+lane]);
  }
}

// ---------------- K3: degree histogram ----------------
__global__ __launch_bounds__(256) void k3_hist(
    const int* __restrict__ dst_po, const int* __restrict__ dst_adj, int* __restrict__ cnt)
{
  int i = blockIdx.x*256 + threadIdx.x;
  if(i < EPO) atomicAdd(&cnt[dst_po[i]], 1);
  else if(i < EPO+EADJ) atomicAdd(&cnt[NI + dst_adj[i-EPO]], 1);
}

// ---------------- K4: scan ----------------
__global__ __launch_bounds__(1024) void k4a_scan(
    const int* __restrict__ cnt, int* __restrict__ offA, int* __restrict__ bsum)
{
  __shared__ int s[1024];
  int y = blockIdx.y;
  int i = blockIdx.x*1024 + threadIdx.x;
  int v = (i<NI) ? cnt[y*NI+i] : 0;
  s[threadIdx.x]=v;
  __syncthreads();
  for(int o=1;o<1024;o<<=1){
    int t = (threadIdx.x>=o) ? s[threadIdx.x-o] : 0;
    __syncthreads();
    s[threadIdx.x] += t;
    __syncthreads();
  }
  if(i<NI) offA[y*NI+i] = s[threadIdx.x]-v;
  if(threadIdx.x==1023) bsum[y*64+blockIdx.x] = s[1023];
}

__global__ __launch_bounds__(128) void k4b_scanb(int* __restrict__ bsum)
{
  int y = threadIdx.x>>6, lane = threadIdx.x&63;
  int v = (lane<49) ? bsum[y*64+lane] : 0;
  int orig = v;
#pragma unroll
  for(int o=1;o<64;o<<=1){
    int t = __shfl_up(v,o,64);
    if(lane>=o) v += t;
  }
  if(lane<49) bsum[y*64+lane] = v-orig;
}

__global__ __launch_bounds__(1024) void k4c_add(
    int* __restrict__ offA, int* __restrict__ cur, const int* __restrict__ bsum)
{
  int y = blockIdx.y;
  int i = blockIdx.x*1024 + threadIdx.x;
  if(i<NI){
    int o = offA[y*NI+i] + bsum[y*64+blockIdx.x];
    offA[y*NI+i]=o;
    cur[y*NI+i]=o;
  }
}

// ---------------- K5 v2: scatter src + per-edge softmax numerator weights ----------------
__global__ __launch_bounds__(256) void k5_scatter(
    const int* __restrict__ src_po, const int* __restrict__ dst_po,
    const int* __restrict__ src_adj, const int* __restrict__ dst_adj,
    const float* __restrict__ a_s_po, const float* __restrict__ a_d_po,
    const float* __restrict__ a_s_adj, const float* __restrict__ a_d_adj,
    int* __restrict__ cur, int* __restrict__ csr_po, int* __restrict__ csr_adj,
    float* __restrict__ pw_po, float* __restrict__ pw_adj)
{
  int i = blockIdx.x*256 + threadIdx.x;
  if(i < EPO){
    int s = src_po[i];
    int d = dst_po[i];
    int p = atomicAdd(&cur[d],1);
    csr_po[p] = s;
    float4 as = *(const float4*)(a_s_po + (size_t)s*4);
    float4 ad = *(const float4*)(a_d_po + (size_t)d*4);
    float4 pv;
    float x;
    x = as.x+ad.x; pv.x = __expf(x>0.f?x:0.2f*x);
    x = as.y+ad.y; pv.y = __expf(x>0.f?x:0.2f*x);
    x = as.z+ad.z; pv.z = __expf(x>0.f?x:0.2f*x);
    x = as.w+ad.w; pv.w = __expf(x>0.f?x:0.2f*x);
    *(float4*)(pw_po + (size_t)p*4) = pv;
  } else if(i < EPO+EADJ){
    int e = i-EPO;
    int s = src_adj[e];
    int d = dst_adj[e];
    int p = atomicAdd(&cur[NI+d],1);
    csr_adj[p] = s;
    float4 as = *(const float4*)(a_s_adj + (size_t)s*4);
    float4 ad = *(const float4*)(a_d_adj + (size_t)d*4);
    float4 pv;
    float x;
    x = as.x+ad.x; pv.x = __expf(x>0.f?x:0.2f*x);
    x = as.y+ad.y; pv.y = __expf(x>0.f?x:0.2f*x);
    x = as.z+ad.z; pv.z = __expf(x>0.f?x:0.2f*x);
    x = as.w+ad.w; pv.w = __expf(x>0.f?x:0.2f*x);
    *(float4*)(pw_adj + (size_t)p*4) = pv;
  }
}

// ---------------- K6 v3: weighted-sum aggregation (weights precomputed) ----------------
__device__ __forceinline__ void agg_rel(
    int beg, int n, int lane,
    const int* __restrict__ csr, const float* __restrict__ pw,
    const u16* __restrict__ emat, u16* __restrict__ aggrow)
{
  float l0=0,l1=0,l2=0,l3=0;
  float c0=0,c1=0,c2=0,c3=0;
  for(int base=0;base<n;base+=64){
    int m = n-base; if(m>64) m=64;
    int sv_ = (lane<m) ? csr[beg+base+lane] : 0;
    int t2=0;
    for(; t2+1<m; t2+=2){
      int s0 = __shfl(sv_, t2, 64);
      int s1 = __shfl(sv_, t2+1, 64);
      float4 p0 = *(const float4*)(pw + (size_t)(beg+base+t2)*4);
      float4 p1 = *(const float4*)(pw + (size_t)(beg+base+t2+1)*4);
      float e0 = bf2f(emat[(size_t)s0*64+lane]);
      float e1 = bf2f(emat[(size_t)s1*64+lane]);
      c0 += p0.x*e0; c1 += p0.y*e0; c2 += p0.z*e0; c3 += p0.w*e0;
      l0 += p0.x;    l1 += p0.y;    l2 += p0.z;    l3 += p0.w;
      c0 += p1.x*e1; c1 += p1.y*e1; c2 += p1.z*e1; c3 += p1.w*e1;
      l0 += p1.x;    l1 += p1.y;    l2 += p1.z;    l3 += p1.w;
    }
    if(t2<m){
      int s0 = __shfl(sv_, t2, 64);
      float4 p0 = *(const float4*)(pw + (size_t)(beg+base+t2)*4);
      float e0 = bf2f(emat[(size_t)s0*64+lane]);
      c0 += p0.x*e0; c1 += p0.y*e0; c2 += p0.z*e0; c3 += p0.w*e0;
      l0 += p0.x;    l1 += p0.y;    l2 += p0.z;    l3 += p0.w;
    }
  }
  aggrow[lane]       = f2bf(n>0 ? c0/l0 : 0.f);
  aggrow[64+lane]    = f2bf(n>0 ? c1/l1 : 0.f);
  aggrow[128+lane]   = f2bf(n>0 ? c2/l2 : 0.f);
  aggrow[192+lane]   = f2bf(n>0 ? c3/l3 : 0.f);
}

__global__ __launch_bounds__(256) void k6_agg(
    const int* __restrict__ off, const int* __restrict__ cnt,
    const int* __restrict__ csr_po, const int* __restrict__ csr_adj,
    const float* __restrict__ pw_po, const float* __restrict__ pw_adj,
    const u16* __restrict__ e_lane, const u16* __restrict__ e_int,
    u16* __restrict__ agg)
{
  int wave=threadIdx.x>>6, lane=threadIdx.x&63;
  int d = blockIdx.x*4 + wave;
  if(d>=NI) return;
  agg_rel(off[d],    cnt[d],    lane, csr_po,  pw_po,  e_lane, agg + (size_t)d*512);
  agg_rel(off[NI+d], cnt[NI+d], lane, csr_adj, pw_adj, e_int,  agg + (size_t)d*512 + 256);
}

// ---------------- GEMM1: per-head block-diagonal projection ----------------
// C[64 rows x 64 cols(head h)] = Ahead[64x128] @ WheadT[h], relu+bias -> inter320 bf16
__global__ __launch_bounds__(256) void gemm_head(
    const u16* __restrict__ agg, const u16* __restrict__ WheadT,
    const float* __restrict__ bias, u16* __restrict__ inter320)
{
  __shared__ u16 As[64][136];
  __shared__ u16 Bs[64][136];
  int t=threadIdx.x, wave=t>>6, lane=t&63;
  int h = blockIdx.y;
  int row0 = blockIdx.x*64;
  int r = lane&15, q = lane>>4;
  const uint4* Bsrc = (const uint4*)(WheadT + (size_t)h*8192);
#pragma unroll
  for(int it=0; it<4; it++){
    int idx = it*256 + t;
    int brow = idx>>4, u4 = idx&15;
    *(uint4*)&Bs[brow][u4*8] = Bsrc[idx];
    int grow = row0 + brow;
    uint4 v = {0,0,0,0};
    if(grow < NI){
      int co = (u4<8) ? (h*64 + u4*8) : (256 + h*64 + (u4-8)*8);
      v = *(const uint4*)(agg + (size_t)grow*512 + co);
    }
    *(uint4*)&As[brow][u4*8] = v;
  }
  __syncthreads();
  f32x4 acc0={0,0,0,0}, acc1={0,0,0,0}, acc2={0,0,0,0}, acc3={0,0,0,0};
#pragma unroll
  for(int ks=0; ks<4; ks++){
    bf16x8 af = *(const bf16x8*)&As[wave*16 + r][q*8 + ks*32];
    bf16x8 b0 = *(const bf16x8*)&Bs[ 0 + r][q*8 + ks*32];
    bf16x8 b1 = *(const bf16x8*)&Bs[16 + r][q*8 + ks*32];
    bf16x8 b2 = *(const bf16x8*)&Bs[32 + r][q*8 + ks*32];
    bf16x8 b3 = *(const bf16x8*)&Bs[48 + r][q*8 + ks*32];
    acc0 = __builtin_amdgcn_mfma_f32_16x16x32_bf16(af,b0,acc0,0,0,0);
    acc1 = __builtin_amdgcn_mfma_f32_16x16x32_bf16(af,b1,acc1,0,0,0);
    acc2 = __builtin_amdgcn_mfma_f32_16x16x32_bf16(af,b2,acc2,0,0,0);
    acc3 = __builtin_amdgcn_mfma_f32_16x16x32_bf16(af,b3,acc3,0,0,0);
  }
  int crow_base = row0 + wave*16 + q*4;
#pragma unroll
  for(int t2=0;t2<4;t2++){
    f32x4 a = (t2==0)?acc0 : (t2==1)?acc1 : (t2==2)?acc2 : acc3;
    int col = h*64 + t2*16 + r;
    float bcol = bias[col];
#pragma unroll
    for(int rr=0;rr<4;rr++){
      int row = crow_base + rr;
      if(row < NI)
        inter320[(size_t)row*320 + col] = f2bf(fmaxf(a[rr]+bcol, 0.f));
    }
  }
}

// ---------------- GEMM2 (dense, K=320): gmat f32 ----------------
__global__ __launch_bounds__(256) void gemm_bf16(
    const u16* __restrict__ A, const u16* __restrict__ BT, int K,
    float* __restrict__ C, int ldc, const float* __restrict__ bias, int N)
{
  __shared__ u16 As[64][40];
  __shared__ u16 Bs[64][40];
  int tid=threadIdx.x, wave=tid>>6, lane=tid&63;
  int row0 = blockIdx.x*64, col0 = blockIdx.y*64;
  int ar = tid>>2, aseg = tid&3;
  int r = lane&15, q = lane>>4;
  f32x4 acc0={0,0,0,0}, acc1={0,0,0,0}, acc2={0,0,0,0}, acc3={0,0,0,0};
  for(int k0=0;k0<K;k0+=32){
    uint4 av = {0,0,0,0};
    int arow = row0+ar;
    if(arow < N) av = *(const uint4*)(A + (size_t)arow*K + k0 + aseg*8);
    uint4 bv = *(const uint4*)(BT + (size_t)(col0+ar)*K + k0 + aseg*8);
    __syncthreads();
    *(uint4*)&As[ar][aseg*8] = av;
    *(uint4*)&Bs[ar][aseg*8] = bv;
    __syncthreads();
    bf16x8 af = *(const bf16x8*)&As[wave*16 + r][q*8];
    bf16x8 b0 = *(const bf16x8*)&Bs[ 0 + r][q*8];
    bf16x8 b1 = *(const bf16x8*)&Bs[16 + r][q*8];
    bf16x8 b2 = *(const bf16x8*)&Bs[32 + r][q*8];
    bf16x8 b3 = *(const bf16x8*)&Bs[48 + r][q*8];
    acc0 = __builtin_amdgcn_mfma_f32_16x16x32_bf16(af,b0,acc0,0,0,0);
    acc1 = __builtin_amdgcn_mfma_f32_16x16x32_bf16(af,b1,acc1,0,0,0);
    acc2 = __builtin_amdgcn_mfma_f32_16x16x32_bf16(af,b2,acc2,0,0,0);
    acc3 = __builtin_amdgcn_mfma_f32_16x16x32_bf16(af,b3,acc3,0,0,0);
  }
  int crow_base = row0 + wave*16 + q*4;
#pragma unroll
  for(int t2=0;t2<4;t2++){
    f32x4 a = (t2==0)?acc0 : (t2==1)?acc1 : (t2==2)?acc2 : acc3;
    int col = col0 + t2*16 + r;
    float bcol = bias[col];
#pragma unroll
    for(int rr=0;rr<4;rr++){
      int row = crow_base + rr;
      if(row < N)
        C[(size_t)row*ldc + col] = a[rr] + bcol;
    }
  }
}

// ---------------- K10: GRU gates + outputs ----------------
__global__ __launch_bounds__(256) void k10_gates(
    const float* __restrict__ gmat, const float* __restrict__ h0,
    const float* __restrict__ Wpi, const float* __restrict__ bpi,
    const float* __restrict__ Wv, const float* __restrict__ bvp,
    float* __restrict__ out)
{
  __shared__ float sWpi[512];
  __shared__ float sWv[64];
  __shared__ float sbpi[8];
  __shared__ float sbv[1];
  for(int i=threadIdx.x;i<512;i+=256) sWpi[i]=Wpi[i];
  if(threadIdx.x<64) sWv[threadIdx.x]=Wv[threadIdx.x];
  if(threadIdx.x<8) sbpi[threadIdx.x]=bpi[threadIdx.x];
  if(threadIdx.x==8) sbv[0]=bvp[0];
  __syncthreads();
  int wave=threadIdx.x>>6, lane=threadIdx.x&63;
  int row = blockIdx.x*4 + wave;
  const float* g = gmat + (size_t)row*256;
  float g0=g[lane], g1=g[64+lane], g2=g[128+lane], g3=g[192+lane];
  float h0v = h0[(size_t)row*64+lane];
  float rr = 1.f/(1.f+__expf(-g0));
  float zz = 1.f/(1.f+__expf(-g1));
  float nn = tanhf(g2 + rr*g3);
  float h = (1.f-zz)*nn + zz*h0v;
  out[450000 + (size_t)row*64 + lane] = h;
  float pk[8];
#pragma unroll
  for(int k2=0;k2<8;k2++) pk[k2] = h*sWpi[lane*8+k2];
  float pv = h*sWv[lane];
#pragma unroll
  for(int o=32;o>0;o>>=1){
#pragma unroll
    for(int k2=0;k2<8;k2++) pk[k2] += __shfl_xor(pk[k2],o,64);
    pv += __shfl_xor(pv,o,64);
  }
  if(lane==0){
#pragma unroll
    for(int k2=0;k2<8;k2++) out[(size_t)row*8+k2] = pk[k2]+sbpi[k2];
    out[400000+row] = pv + sbv[0];
  }
}

extern "C" void kernel_launch(void* const* d_in, const int* in_sizes, int n_in,
                              void* d_out, int out_size, void* d_ws, size_t ws_size,
                              hipStream_t stream) {
  const float* x_int      = (const float*)d_in[0];
  const float* x_lane     = (const float*)d_in[1];
  const float* h0         = (const float*)d_in[2];
  const float* enc_int_W  = (const float*)d_in[3];
  const float* enc_int_b  = (const float*)d_in[4];
  const float* enc_lane_W = (const float*)d_in[5];
  const float* enc_lane_b = (const float*)d_in[6];
  const float* Wsrc_po    = (const float*)d_in[7];
  const float* Wdst_po    = (const float*)d_in[8];
  const float* att_src_po = (const float*)d_in[9];
  const float* att_dst_po = (const float*)d_in[10];
  const float* bias_po    = (const float*)d_in[11];
  const float* Wsrc_adj   = (const float*)d_in[12];
  const float* Wdst_adj   = (const float*)d_in[13];
  const float* att_src_adj= (const float*)d_in[14];
  const float* att_dst_adj= (const float*)d_in[15];
  const float* bias_adj   = (const float*)d_in[16];
  const float* gru_W_ih   = (const float*)d_in[17];
  const float* gru_W_hh   = (const float*)d_in[18];
  const float* gru_b_ih   = (const float*)d_in[19];
  const float* gru_b_hh   = (const float*)d_in[20];
  const float* W_pi       = (const float*)d_in[21];
  const float* b_pi       = (const float*)d_in[22];
  const float* W_v        = (const float*)d_in[23];
  const float* b_v        = (const float*)d_in[24];
  const int* src_po  = (const int*)d_in[25];
  const int* dst_po  = (const int*)d_in[26];
  const int* src_adj = (const int*)d_in[27];
  const int* dst_adj = (const int*)d_in[28];
  float* out = (float*)d_out;

  char* w = (char*)d_ws;
  size_t ofs = 0;
  auto alloc = [&](size_t bytes)->char*{
    char* p = w + ofs;
    ofs = (ofs + bytes + 255) & ~(size_t)255;
    return p;
  };
  u16*  e_lane   = (u16*)alloc((size_t)NL*64*2);   // aliased as gmat later
  float* gmat    = (float*)e_lane;                 // NI*256*4 == NL*64*2
  u16*  e_int    = (u16*)alloc((size_t)NI*64*2);
  float* a_s_po  = (float*)alloc((size_t)NL*4*4);
  float* a_d_po  = (float*)alloc((size_t)NI*4*4);
  float* a_s_adj = (float*)alloc((size_t)NI*4*4);
  float* a_d_adj = (float*)alloc((size_t)NI*4*4);
  int*  cnt      = (int*)alloc((size_t)2*NI*4);
  int*  offA     = (int*)alloc((size_t)2*NI*4);
  int*  cur      = (int*)alloc((size_t)2*NI*4);
  int*  csr_po   = (int*)alloc((size_t)EPO*4);
  int*  csr_adj  = (int*)alloc((size_t)EADJ*4);
  float* pw_po   = (float*)alloc((size_t)EPO*4*4);
  float* pw_adj  = (float*)alloc((size_t)EADJ*4*4);
  int*  bsum     = (int*)alloc(2*64*4);
  u16*  agg      = (u16*)alloc((size_t)NI*512*2);
  u16*  inter320 = (u16*)alloc((size_t)NI*320*2);
  u16*  WheadT   = (u16*)alloc(4*64*128*2);
  u16*  B2T      = (u16*)alloc(256*320*2);
  float* v4      = (float*)alloc(4*256*4);
  float* bias_comb = (float*)alloc(256*4);
  float* bias2   = (float*)alloc(256*4);
  (void)ws_size; (void)n_in; (void)in_sizes; (void)out_size;

  kz<<<(2*NI+255)/256, 256, 0, stream>>>(cnt, 2*NI);
  k0_prep<<<256, 256, 0, stream>>>(
      Wsrc_po, att_src_po, Wdst_po, att_dst_po,
      Wsrc_adj, att_src_adj, Wdst_adj, att_dst_adj,
      gru_W_ih, gru_W_hh, bias_po, bias_adj, gru_b_ih, gru_b_hh,
      v4, WheadT, B2T, bias_comb, bias2);
  k1_enc_lane<<<(NL+255)/256, 256, 0, stream>>>(x_lane, enc_lane_W, enc_lane_b,
      v4 + 0, e_lane, a_s_po);
  k2_enc_int<<<(NI+255)/256, 256, 0, stream>>>(x_int, enc_int_W, enc_int_b,
      v4 + 256, v4 + 512, v4 + 768, h0,
      e_int, a_d_po, a_s_adj, a_d_adj, inter320);
  k3_hist<<<(EPO+EADJ+255)/256, 256, 0, stream>>>(dst_po, dst_adj, cnt);
  k4a_scan<<<dim3(49,2), 1024, 0, stream>>>(cnt, offA, bsum);
  k4b_scanb<<<1, 128, 0, stream>>>(bsum);
  k4c_add<<<dim3(49,2), 1024, 0, stream>>>(offA, cur, bsum);
  k5_scatter<<<(EPO+EADJ+255)/256, 256, 0, stream>>>(src_po, dst_po, src_adj, dst_adj,
      a_s_po, a_d_po, a_s_adj, a_d_adj,
      cur, csr_po, csr_adj, pw_po, pw_adj);
  k6_agg<<<(NI+3)/4, 256, 0, stream>>>(offA, cnt, csr_po, csr_adj,
      pw_po, pw_adj, e_lane, e_int, agg);
  gemm_head<<<dim3((NI+63)/64, 4), 256, 0, stream>>>(agg, WheadT, bias_comb, inter320);
  gemm_bf16<<<dim3((NI+63)/64, 4), 256, 0, stream>>>(inter320, B2T, 320, gmat, 256, bias2, NI);
  k10_gates<<<NI/4, 256, 0, stream>>>(gmat, h0, W_pi, b_pi, W_v, b_v, out);
}